// Round 2
// baseline (37289.758 us; speedup 1.0000x reference)
//
#include <hip/hip_runtime.h>
#include <math.h>

#define Bz 32
#define Tz 512
#define Ez 256
#define Hz 512
#define FCH 446   // 180 conv + 10 rev + 256 x

__device__ __forceinline__ float sigf(float x){ return 1.0f/(1.0f + __expf(-x)); }
__device__ __forceinline__ float tanhfast(float x){ return 1.0f - 2.0f/(__expf(2.0f*x) + 1.0f); }

// ---------------- WhT transpose: WhT[c*512 + k] = Wh[k*2048 + c] ----------------
__global__ __launch_bounds__(256) void k_transpose_wh(const float* __restrict__ Wh, float* __restrict__ WhT){
  int idx = blockIdx.x*256 + threadIdx.x;      // 512*2048 = 1,048,576
  int k = idx >> 11, c = idx & 2047;
  WhT[c*512 + k] = Wh[idx];
}

// ---------------- conv (3 kernels, SAME pad) + rxw = x_rev @ rev_Wx ----------------
__global__ __launch_bounds__(256) void k_conv(
    const float* __restrict__ x,
    const float* __restrict__ w1, const float* __restrict__ b1,
    const float* __restrict__ w2, const float* __restrict__ b2,
    const float* __restrict__ w3, const float* __restrict__ b3,
    const float* __restrict__ rwx,
    float* __restrict__ feat, float* __restrict__ rxw)
{
  __shared__ __align__(16) float xs[256*40];   // xs[e*40 + i] = x[b][t0-2+i], i in 0..35
  int b  = blockIdx.x >> 4;
  int t0 = (blockIdx.x & 15) * 32;
  int tid = threadIdx.x;
  for (int i = 0; i < 36; ++i){
    int t = t0 - 2 + i;
    xs[tid*40 + i] = (t >= 0 && t < Tz) ? x[(b*Tz + t)*Ez + tid] : 0.0f;
  }
  __syncthreads();
  int tq = tid & 7, cs = tid >> 3;             // 8 t-quads x 32 c-slots
  float acc[6][4];
  float racc[2][4];
  #pragma unroll
  for (int ci = 0; ci < 6; ++ci){
    int c = cs + 32*ci;
    float bv = 0.0f;
    if (c < 60) bv = b1[c];
    else if (c < 120) bv = b2[c-60];
    else if (c < 180) bv = b3[c-120];
    acc[ci][0]=acc[ci][1]=acc[ci][2]=acc[ci][3]=bv;
  }
  #pragma unroll
  for (int ji = 0; ji < 2; ++ji){ racc[ji][0]=racc[ji][1]=racc[ji][2]=racc[ji][3]=0.0f; }

  for (int e = 0; e < 256; ++e){
    const float* xr = &xs[e*40 + 4*tq];
    float4 wa = *(const float4*)(xr);
    float4 wb = *(const float4*)(xr + 4);
    float wd[8] = {wa.x, wa.y, wa.z, wa.w, wb.x, wb.y, wb.z, wb.w};
    #pragma unroll
    for (int ci = 0; ci < 6; ++ci){
      int c = cs + 32*ci;
      if (c < 60){
        #pragma unroll
        for (int k = 0; k < 3; ++k){
          float wv = w1[(k*256 + e)*60 + c];
          #pragma unroll
          for (int j = 0; j < 4; ++j) acc[ci][j] = fmaf(wd[1 + j + k], wv, acc[ci][j]);
        }
      } else if (c < 120){
        int cc = c - 60;
        #pragma unroll
        for (int k = 0; k < 4; ++k){
          float wv = w2[(k*256 + e)*60 + cc];
          #pragma unroll
          for (int j = 0; j < 4; ++j) acc[ci][j] = fmaf(wd[1 + j + k], wv, acc[ci][j]);
        }
      } else if (c < 180){
        int cc = c - 120;
        #pragma unroll
        for (int k = 0; k < 5; ++k){
          float wv = w3[(k*256 + e)*60 + cc];
          #pragma unroll
          for (int j = 0; j < 4; ++j) acc[ci][j] = fmaf(wd[j + k], wv, acc[ci][j]);
        }
      }
    }
    #pragma unroll
    for (int ji = 0; ji < 2; ++ji){
      int jc = cs + 32*ji;
      if (jc < 40){
        float wv = rwx[e*40 + jc];
        #pragma unroll
        for (int j = 0; j < 4; ++j) racc[ji][j] = fmaf(wd[2 + j], wv, racc[ji][j]);
      }
    }
  }
  #pragma unroll
  for (int ci = 0; ci < 6; ++ci){
    int c = cs + 32*ci;
    if (c < 180){
      #pragma unroll
      for (int j = 0; j < 4; ++j){
        int t = t0 + 4*tq + j;
        if (t >= 1) feat[((t-1)*Bz + b)*FCH + c] = acc[ci][j];
      }
    }
  }
  #pragma unroll
  for (int ji = 0; ji < 2; ++ji){
    int jc = cs + 32*ji;
    if (jc < 40){
      #pragma unroll
      for (int j = 0; j < 4; ++j){
        int t = t0 + 4*tq + j;
        rxw[((511 - t)*Bz + b)*40 + jc] = racc[ji][j];
      }
    }
  }
}

// ---------------- copy x into feat[...,190:446] ----------------
__global__ __launch_bounds__(256) void k_featx(const float* __restrict__ x, float* __restrict__ feat){
  int bt = blockIdx.x;
  int b = bt >> 9, t = bt & 511;
  feat[(t*Bz + b)*FCH + 190 + threadIdx.x] = x[(b*Tz + t)*Ez + threadIdx.x];
}

// ---------------- reverse LSTM (hidden 10), one wave per batch row ----------------
__global__ __launch_bounds__(64) void k_rev(const float* __restrict__ rxw,
    const float* __restrict__ revWh, const float* __restrict__ revb, float* __restrict__ feat){
  int b = blockIdx.x;
  int j = threadIdx.x;
  float wreg[10];
  float bias = 0.0f;
  #pragma unroll
  for (int k = 0; k < 10; ++k) wreg[k] = 0.0f;
  if (j < 40){
    bias = revb[j];
    #pragma unroll
    for (int k = 0; k < 10; ++k) wreg[k] = revWh[k*40 + j];
  }
  float h[10];
  #pragma unroll
  for (int k = 0; k < 10; ++k) h[k] = 0.0f;
  float c = 0.0f;
  for (int s = 0; s < Tz; ++s){
    float z = bias + ((j < 40) ? rxw[(s*Bz + b)*40 + j] : 0.0f);
    #pragma unroll
    for (int k = 0; k < 10; ++k) z = fmaf(h[k], wreg[k], z);
    float a = (j >= 20 && j < 30) ? tanhfast(z) : sigf(z);
    float af = __shfl(a, j + 10);
    float ag = __shfl(a, j + 20);
    float ao = __shfl(a, j + 30);
    if (j < 10) c = af*c + a*ag;
    float hn = ao * tanhfast(c);
    #pragma unroll
    for (int k = 0; k < 10; ++k) h[k] = __shfl(hn, k);
    if (j < 10 && s >= 1) feat[((s-1)*Bz + b)*FCH + 180 + j] = hn;
  }
}

// ---------------- hid = relu(feat @ d0_W + d0_b): 32 rows x 100 cols per block ----------------
__global__ __launch_bounds__(256) void k_hid(const float* __restrict__ feat,
    const float* __restrict__ d0W, const float* __restrict__ d0b, float* __restrict__ hid){
  __shared__ __align__(16) float fT[446*36];   // fT[ch*36 + r]
  int r0 = blockIdx.x * 32;
  int tid = threadIdx.x;
  for (int r = 0; r < 32; ++r){
    fT[tid*36 + r] = feat[(r0 + r)*FCH + tid];
    if (tid < 190) fT[(tid + 256)*36 + r] = feat[(r0 + r)*FCH + tid + 256];
  }
  __syncthreads();
  int cs = tid & 31, rq = tid >> 5;            // 32 c-slots (4 cols each), 8 row-quads
  if (cs < 25){
    float4 accv[4];
    #pragma unroll
    for (int jc = 0; jc < 4; ++jc) accv[jc] = make_float4(0.f,0.f,0.f,0.f);
    for (int k = 0; k < 446; ++k){
      float4 xv = *(const float4*)&fT[k*36 + 4*rq];
      float4 wv = *(const float4*)&d0W[k*100 + 4*cs];
      accv[0].x = fmaf(xv.x, wv.x, accv[0].x); accv[0].y = fmaf(xv.y, wv.x, accv[0].y);
      accv[0].z = fmaf(xv.z, wv.x, accv[0].z); accv[0].w = fmaf(xv.w, wv.x, accv[0].w);
      accv[1].x = fmaf(xv.x, wv.y, accv[1].x); accv[1].y = fmaf(xv.y, wv.y, accv[1].y);
      accv[1].z = fmaf(xv.z, wv.y, accv[1].z); accv[1].w = fmaf(xv.w, wv.y, accv[1].w);
      accv[2].x = fmaf(xv.x, wv.z, accv[2].x); accv[2].y = fmaf(xv.y, wv.z, accv[2].y);
      accv[2].z = fmaf(xv.z, wv.z, accv[2].z); accv[2].w = fmaf(xv.w, wv.z, accv[2].w);
      accv[3].x = fmaf(xv.x, wv.w, accv[3].x); accv[3].y = fmaf(xv.y, wv.w, accv[3].y);
      accv[3].z = fmaf(xv.z, wv.w, accv[3].z); accv[3].w = fmaf(xv.w, wv.w, accv[3].w);
    }
    #pragma unroll
    for (int i = 0; i < 4; ++i){
      int row = r0 + 4*rq + i;
      float4 o;
      float vi[4] = { i==0?accv[0].x:(i==1?accv[0].y:(i==2?accv[0].z:accv[0].w)),
                      i==0?accv[1].x:(i==1?accv[1].y:(i==2?accv[1].z:accv[1].w)),
                      i==0?accv[2].x:(i==1?accv[2].y:(i==2?accv[2].z:accv[2].w)),
                      i==0?accv[3].x:(i==1?accv[3].y:(i==2?accv[3].z:accv[3].w)) };
      o.x = fmaxf(vi[0] + d0b[4*cs+0], 0.0f);
      o.y = fmaxf(vi[1] + d0b[4*cs+1], 0.0f);
      o.z = fmaxf(vi[2] + d0b[4*cs+2], 0.0f);
      o.w = fmaxf(vi[3] + d0b[4*cs+3], 0.0f);
      *(float4*)&hid[row*100 + 4*cs] = o;
    }
  }
}

// ---------------- pi + gumbel softmax -> d0,d1 (64 rows per block) ----------------
__global__ __launch_bounds__(128) void k_pi(const float* __restrict__ hid,
    const float* __restrict__ d1W, const float* __restrict__ d1b,
    const float* __restrict__ gum, float* __restrict__ d0a, float* __restrict__ d1a){
  __shared__ float hidL[64*100];
  int r0 = blockIdx.x * 64;
  int tid = threadIdx.x;
  for (int i = 0; i < 50; ++i) hidL[tid + 128*i] = hid[r0*100 + tid + 128*i];
  __syncthreads();
  int r = tid >> 1, pp = tid & 1;
  float s = d1b[pp];
  for (int m = 0; m < 100; ++m) s = fmaf(hidL[r*100 + m], d1W[m*2 + pp], s);
  int row = r0 + r;
  float a = (s + gum[row*2 + pp]) / 1e-5f;
  float other = __shfl_xor(a, 1);
  float mx = fmaxf(a, other);
  float ea = expf(a - mx), eb = expf(other - mx);
  float d = ea / (ea + eb);
  if (pp == 0) d0a[row] = d; else d1a[row] = d;
}

// ---------------- xzT[t][col][b] = x[b][t] @ cell_Wx + cell_b ----------------
__global__ __launch_bounds__(256) void k_xz(const float* __restrict__ x,
    const float* __restrict__ Wx, const float* __restrict__ cb, float* __restrict__ xzT){
  __shared__ __align__(16) float xT[256*36];   // xT[e*36 + b]
  int t  = blockIdx.x >> 4;
  int c0 = (blockIdx.x & 15) * 128;
  int tid = threadIdx.x;
  for (int b = 0; b < 32; ++b){
    xT[tid*36 + b] = x[(b*Tz + t)*Ez + tid];
  }
  __syncthreads();
  int cs = tid & 31, rq = tid >> 5;
  float4 accv[4];
  #pragma unroll
  for (int jc = 0; jc < 4; ++jc) accv[jc] = make_float4(0.f,0.f,0.f,0.f);
  for (int e = 0; e < 256; ++e){
    float4 xv = *(const float4*)&xT[e*36 + 4*(rq & 7)];
    float4 wv = *(const float4*)&Wx[e*2048 + c0 + 4*cs];
    accv[0].x = fmaf(xv.x, wv.x, accv[0].x); accv[0].y = fmaf(xv.y, wv.x, accv[0].y);
    accv[0].z = fmaf(xv.z, wv.x, accv[0].z); accv[0].w = fmaf(xv.w, wv.x, accv[0].w);
    accv[1].x = fmaf(xv.x, wv.y, accv[1].x); accv[1].y = fmaf(xv.y, wv.y, accv[1].y);
    accv[1].z = fmaf(xv.z, wv.y, accv[1].z); accv[1].w = fmaf(xv.w, wv.y, accv[1].w);
    accv[2].x = fmaf(xv.x, wv.z, accv[2].x); accv[2].y = fmaf(xv.y, wv.z, accv[2].y);
    accv[2].z = fmaf(xv.z, wv.z, accv[2].z); accv[2].w = fmaf(xv.w, wv.z, accv[2].w);
    accv[3].x = fmaf(xv.x, wv.w, accv[3].x); accv[3].y = fmaf(xv.y, wv.w, accv[3].y);
    accv[3].z = fmaf(xv.z, wv.w, accv[3].z); accv[3].w = fmaf(xv.w, wv.w, accv[3].w);
  }
  #pragma unroll
  for (int jc = 0; jc < 4; ++jc){
    int col = c0 + 4*cs + jc;
    float bv = cb[col];
    float4 o = accv[jc];
    o.x += bv; o.y += bv; o.z += bv; o.w += bv;
    *(float4*)&xzT[((size_t)t*2048 + col)*32 + 4*rq] = o;
  }
}

// ---------------- persistent scan kernel ----------------
// 256 blocks x 1024 threads. group g = blockIdx%8 (XCD under round-robin),
// member m = blockIdx/8 (0..31). Group handles batches 4g..4g+3; member owns
// hidden units j in [16m,16m+16) => 64 z-cols, weights resident in LDS.
// Cross-block sync = group-local monotonic counter barrier (agent scope).
// LDS 142.6 KB => 1 block/CU => all 256 blocks co-resident => no deadlock.
__global__ __launch_bounds__(1024, 4) void k_scan(
    const float* __restrict__ WhT, const float* __restrict__ xzT,
    const float* __restrict__ d0a, const float* __restrict__ d1a,
    float* __restrict__ hG,              // [8][2][4*512]
    unsigned int* __restrict__ barc,     // [8] stride-64 uints (256B apart)
    float* __restrict__ out)
{
  __shared__ __align__(16) float wL[64*516];   // 132096 B, +4 pad breaks bank stride
  __shared__ __align__(16) float hL[4*516];    // 8256 B
  __shared__ float part[1024];
  __shared__ float zL[256];
  __shared__ float cL[64];
  __shared__ float hcandL[64];

  int tid = threadIdx.x;
  int g = blockIdx.x & 7;
  int m = blockIdx.x >> 3;

  // one-time: load 64-col weight slice into LDS (128 KB from global)
  {
    int c = tid >> 4;                    // 0..63
    int f = tid & 15;
    int col = ((c >> 4) << 9) + (m << 4) + (c & 15);
    const float4* src = (const float4*)(WhT + (size_t)col*512);
    #pragma unroll
    for (int i = 0; i < 8; ++i){
      float4 v = src[f + 16*i];
      *(float4*)&wL[c*516 + 4*(f + 16*i)] = v;
    }
  }
  if (tid < 64) cL[tid] = 0.0f;
  __syncthreads();

  // thread mapping: tid = b + 4*c + 256*kq  (b:4, c:64 z-cols, kq:4 K-quarters)
  int b  = tid & 3;
  int c  = (tid >> 2) & 63;
  int kq = tid >> 8;
  int col = ((c >> 4) << 9) + (m << 4) + (c & 15);
  int Bg  = (g << 2) + b;                // global batch for pair threads

  unsigned int* cnt = barc + g*64;
  float* hg0 = hG + (size_t)(g*2 + 0) * (4*512);
  float* hg1 = hG + (size_t)(g*2 + 1) * (4*512);

  for (int t = 0; t < Tz; ++t){
    const float* hcur = (t & 1) ? hg1 : hg0;
    float*       hnxt = (t & 1) ? hg0 : hg1;

    // stage group h into LDS (8 KB, XCD-L2 local)
    if (tid < 512){
      int bb = tid >> 7, k4 = (tid & 127) << 2;
      float4 v = *(const float4*)(hcur + bb*512 + k4);
      *(float4*)&hL[bb*516 + k4] = v;
    }
    // prefetch xz + gate coefficients (latency hidden under matvec)
    float xzv = 0.0f;
    if (tid < 256) xzv = xzT[((size_t)t*2048 + col)*32 + Bg];
    float dv0 = 0.0f, dv1 = 0.0f;
    if (tid < 64){
      dv0 = d0a[t*32 + ((g << 2) + (tid & 3))];
      dv1 = d1a[t*32 + ((g << 2) + (tid & 3))];
    }
    __syncthreads();

    // partial matvec: this thread: z-col `col`, batch b, k in [kq*128, kq*128+128)
    float acc = 0.0f;
    const float* hp = &hL[b*516 + (kq << 7)];
    const float* wp = &wL[c*516 + (kq << 7)];
    #pragma unroll
    for (int kk = 0; kk < 16; ++kk){
      float4 hv0 = *(const float4*)(hp + 8*kk);
      float4 hv1 = *(const float4*)(hp + 8*kk + 4);
      float4 wv0 = *(const float4*)(wp + 8*kk);
      float4 wv1 = *(const float4*)(wp + 8*kk + 4);
      acc = fmaf(hv0.x, wv0.x, acc); acc = fmaf(hv0.y, wv0.y, acc);
      acc = fmaf(hv0.z, wv0.z, acc); acc = fmaf(hv0.w, wv0.w, acc);
      acc = fmaf(hv1.x, wv1.x, acc); acc = fmaf(hv1.y, wv1.y, acc);
      acc = fmaf(hv1.z, wv1.z, acc); acc = fmaf(hv1.w, wv1.w, acc);
    }
    part[tid] = acc;
    __syncthreads();

    if (tid < 256){
      float s = part[tid] + part[tid+256] + part[tid+512] + part[tid+768] + xzv;
      zL[tid] = s;
    }
    __syncthreads();

    if (tid < 64){
      int jl = tid >> 2, bb = tid & 3;
      float zi = zL[bb + 4*jl];
      float zf = zL[bb + 4*jl + 64];
      float zg = zL[bb + 4*jl + 128];
      float zo = zL[bb + 4*jl + 192];
      float cold = cL[tid];
      float hold = hL[bb*516 + (m << 4) + jl];
      float ccand = sigf(zf)*cold + sigf(zi)*tanhfast(zg);
      float hcand = sigf(zo)*tanhfast(ccand);
      cL[tid] = dv0*ccand + dv1*cold;
      hcandL[bb*16 + jl] = hcand;
      hnxt[bb*512 + (m << 4) + jl] = dv0*hcand + dv1*hold;
    }
    __syncthreads();

    // out store by wave 1 (keeps wave 0's fence free of these stores)
    if (tid >= 64 && tid < 80){
      int idx = tid - 64; int bb = idx >> 2, q = idx & 3;
      float4 v = *(const float4*)&hcandL[bb*16 + 4*q];
      *(float4*)(out + (size_t)((g << 2) + bb)*(Tz*Hz) + (size_t)t*Hz + (m << 4) + 4*q) = v;
    }

    if (t < Tz-1){
      if (tid < 64) __threadfence();     // publish wave 0's hnxt stores device-wide
      __syncthreads();
      if (tid == 0){
        __hip_atomic_fetch_add(cnt, 1u, __ATOMIC_RELEASE, __HIP_MEMORY_SCOPE_AGENT);
        unsigned int target = 32u*(unsigned)(t+1);
        while (__hip_atomic_load(cnt, __ATOMIC_ACQUIRE, __HIP_MEMORY_SCOPE_AGENT) < target)
          __builtin_amdgcn_s_sleep(1);
      }
      __syncthreads();
      __threadfence();                   // invalidate L1 before re-reading hG
    }
  }
}

extern "C" void kernel_launch(void* const* d_in, const int* in_sizes, int n_in,
                              void* d_out, int out_size, void* d_ws, size_t ws_size,
                              hipStream_t stream)
{
  const float* x       = (const float*)d_in[0];
  const float* conv1_w = (const float*)d_in[1];
  const float* conv1_b = (const float*)d_in[2];
  const float* conv2_w = (const float*)d_in[3];
  const float* conv2_b = (const float*)d_in[4];
  const float* conv3_w = (const float*)d_in[5];
  const float* conv3_b = (const float*)d_in[6];
  const float* rev_Wx  = (const float*)d_in[7];
  const float* rev_Wh  = (const float*)d_in[8];
  const float* rev_b   = (const float*)d_in[9];
  const float* d0_W    = (const float*)d_in[10];
  const float* d0_b    = (const float*)d_in[11];
  const float* d1_W    = (const float*)d_in[12];
  const float* d1_b    = (const float*)d_in[13];
  const float* cell_Wx = (const float*)d_in[14];
  const float* cell_Wh = (const float*)d_in[15];
  const float* cell_b  = (const float*)d_in[16];
  const float* gumbel  = (const float*)d_in[17];
  float* out = (float*)d_out;

  char* ws = (char*)d_ws;
  size_t off = 0;
  float* xzT  = (float*)(ws + off); off += (size_t)Tz*2048*Bz*4;       // 134 MB
  float* feat = (float*)(ws + off); off += (size_t)Tz*Bz*FCH*4;        // 29 MB
  float* WhT  = (float*)(ws + off); off += (size_t)Hz*2048*4;          // 4 MB
  float* rxw  = (float*)(ws + off); off += (size_t)Tz*Bz*40*4;         // 2.6 MB
  float* hid  = (float*)(ws + off); off += (size_t)Tz*Bz*100*4;        // 6.5 MB
  float* d0a  = (float*)(ws + off); off += (size_t)Tz*Bz*4;
  float* d1a  = (float*)(ws + off); off += (size_t)Tz*Bz*4;
  float* hG   = (float*)(ws + off); off += (size_t)8*2*4*512*4;        // 128 KB
  unsigned int* barc = (unsigned int*)(ws + off); off += 8*64*4;       // 2 KB

  // zero-init: feat row T-1 (ff tail zeros), h double-buffers, barrier counters
  hipMemsetAsync(feat + (size_t)(Tz-1)*Bz*FCH, 0, Bz*FCH*4, stream);
  hipMemsetAsync(hG, 0, (size_t)8*2*4*512*4, stream);
  hipMemsetAsync(barc, 0, 8*64*4, stream);

  k_transpose_wh<<<4096, 256, 0, stream>>>(cell_Wh, WhT);
  k_conv<<<512, 256, 0, stream>>>(x, conv1_w, conv1_b, conv2_w, conv2_b,
                                  conv3_w, conv3_b, rev_Wx, feat, rxw);
  k_featx<<<16384, 256, 0, stream>>>(x, feat);
  k_rev<<<32, 64, 0, stream>>>(rxw, rev_Wh, rev_b, feat);
  k_hid<<<512, 256, 0, stream>>>(feat, d0_W, d0_b, hid);
  k_pi<<<256, 128, 0, stream>>>(hid, d1_W, d1_b, gumbel, d0a, d1a);
  k_xz<<<8192, 256, 0, stream>>>(x, cell_Wx, cell_b, xzT);

  k_scan<<<256, 1024, 0, stream>>>(WhT, xzT, d0a, d1a, hG, barc, out);
}

// Round 3
// 3115.318 us; speedup vs baseline: 11.9698x; 11.9698x over previous
//
#include <hip/hip_runtime.h>
#include <math.h>

#define Bz 32
#define Tz 512
#define Ez 256
#define Hz 512
#define FCH 446   // 180 conv + 10 rev + 256 x

__device__ __forceinline__ float sigf(float x){ return 1.0f/(1.0f + __expf(-x)); }
__device__ __forceinline__ float tanhfast(float x){ return 1.0f - 2.0f/(__expf(2.0f*x) + 1.0f); }

// ---------------- WhT transpose: WhT[c*512 + k] = Wh[k*2048 + c] ----------------
__global__ __launch_bounds__(256) void k_transpose_wh(const float* __restrict__ Wh, float* __restrict__ WhT){
  int idx = blockIdx.x*256 + threadIdx.x;      // 512*2048 = 1,048,576
  int k = idx >> 11, c = idx & 2047;
  WhT[c*512 + k] = Wh[idx];
}

// ---------------- conv (3 kernels, SAME pad) + rxw = x_rev @ rev_Wx + x-copy into feat ----
__global__ __launch_bounds__(256) void k_conv(
    const float* __restrict__ x,
    const float* __restrict__ w1, const float* __restrict__ b1,
    const float* __restrict__ w2, const float* __restrict__ b2,
    const float* __restrict__ w3, const float* __restrict__ b3,
    const float* __restrict__ rwx,
    float* __restrict__ feat, float* __restrict__ rxw)
{
  __shared__ __align__(16) float xs[256*40];   // xs[e*40 + i] = x[b][t0-2+i], i in 0..35
  int b  = blockIdx.x >> 4;
  int t0 = (blockIdx.x & 15) * 32;
  int tid = threadIdx.x;
  for (int i = 0; i < 36; ++i){
    int t = t0 - 2 + i;
    xs[tid*40 + i] = (t >= 0 && t < Tz) ? x[(b*Tz + t)*Ez + tid] : 0.0f;
  }
  __syncthreads();
  // x-part of d0 input: feat[t][b][190+e] = x[b][t][e]  (current t, not shifted)
  for (int i = 0; i < 32; ++i){
    int t = t0 + i;
    feat[((size_t)t*Bz + b)*FCH + 190 + tid] = xs[tid*40 + i + 2];
  }
  int tq = tid & 7, cs = tid >> 3;             // 8 t-quads x 32 c-slots
  float acc[6][4];
  float racc[2][4];
  #pragma unroll
  for (int ci = 0; ci < 6; ++ci){
    int c = cs + 32*ci;
    float bv = 0.0f;
    if (c < 60) bv = b1[c];
    else if (c < 120) bv = b2[c-60];
    else if (c < 180) bv = b3[c-120];
    acc[ci][0]=acc[ci][1]=acc[ci][2]=acc[ci][3]=bv;
  }
  #pragma unroll
  for (int ji = 0; ji < 2; ++ji){ racc[ji][0]=racc[ji][1]=racc[ji][2]=racc[ji][3]=0.0f; }

  for (int e = 0; e < 256; ++e){
    const float* xr = &xs[e*40 + 4*tq];
    float4 wa = *(const float4*)(xr);
    float4 wb = *(const float4*)(xr + 4);
    float wd[8] = {wa.x, wa.y, wa.z, wa.w, wb.x, wb.y, wb.z, wb.w};
    #pragma unroll
    for (int ci = 0; ci < 6; ++ci){
      int c = cs + 32*ci;
      if (c < 60){
        #pragma unroll
        for (int k = 0; k < 3; ++k){
          float wv = w1[(k*256 + e)*60 + c];
          #pragma unroll
          for (int j = 0; j < 4; ++j) acc[ci][j] = fmaf(wd[1 + j + k], wv, acc[ci][j]);
        }
      } else if (c < 120){
        int cc = c - 60;
        #pragma unroll
        for (int k = 0; k < 4; ++k){
          float wv = w2[(k*256 + e)*60 + cc];
          #pragma unroll
          for (int j = 0; j < 4; ++j) acc[ci][j] = fmaf(wd[1 + j + k], wv, acc[ci][j]);
        }
      } else if (c < 180){
        int cc = c - 120;
        #pragma unroll
        for (int k = 0; k < 5; ++k){
          float wv = w3[(k*256 + e)*60 + cc];
          #pragma unroll
          for (int j = 0; j < 4; ++j) acc[ci][j] = fmaf(wd[j + k], wv, acc[ci][j]);
        }
      }
    }
    #pragma unroll
    for (int ji = 0; ji < 2; ++ji){
      int jc = cs + 32*ji;
      if (jc < 40){
        float wv = rwx[e*40 + jc];
        #pragma unroll
        for (int j = 0; j < 4; ++j) racc[ji][j] = fmaf(wd[2 + j], wv, racc[ji][j]);
      }
    }
  }
  #pragma unroll
  for (int ci = 0; ci < 6; ++ci){
    int c = cs + 32*ci;
    if (c < 180){
      #pragma unroll
      for (int j = 0; j < 4; ++j){
        int t = t0 + 4*tq + j;
        if (t >= 1) feat[((size_t)(t-1)*Bz + b)*FCH + c] = acc[ci][j];
      }
    }
  }
  #pragma unroll
  for (int ji = 0; ji < 2; ++ji){
    int jc = cs + 32*ji;
    if (jc < 40){
      #pragma unroll
      for (int j = 0; j < 4; ++j){
        int t = t0 + 4*tq + j;
        rxw[((size_t)(511 - t)*Bz + b)*40 + jc] = racc[ji][j];
      }
    }
  }
}

// ---------------- reverse LSTM (hidden 10), one wave per batch row ----------------
__global__ __launch_bounds__(64) void k_rev(const float* __restrict__ rxw,
    const float* __restrict__ revWh, const float* __restrict__ revb, float* __restrict__ feat){
  int b = blockIdx.x;
  int j = threadIdx.x;
  float wreg[10];
  float bias = 0.0f;
  #pragma unroll
  for (int k = 0; k < 10; ++k) wreg[k] = 0.0f;
  if (j < 40){
    bias = revb[j];
    #pragma unroll
    for (int k = 0; k < 10; ++k) wreg[k] = revWh[k*40 + j];
  }
  float h[10];
  #pragma unroll
  for (int k = 0; k < 10; ++k) h[k] = 0.0f;
  float c = 0.0f;
  for (int s = 0; s < Tz; ++s){
    float z = bias + ((j < 40) ? rxw[(s*Bz + b)*40 + j] : 0.0f);
    #pragma unroll
    for (int k = 0; k < 10; ++k) z = fmaf(h[k], wreg[k], z);
    float a = (j >= 20 && j < 30) ? tanhfast(z) : sigf(z);
    float af = __shfl(a, j + 10);
    float ag = __shfl(a, j + 20);
    float ao = __shfl(a, j + 30);
    if (j < 10) c = af*c + a*ag;
    float hn = ao * tanhfast(c);
    #pragma unroll
    for (int k = 0; k < 10; ++k) h[k] = __shfl(hn, k);
    if (j < 10 && s >= 1) feat[((size_t)(s-1)*Bz + b)*FCH + 180 + j] = hn;
  }
}

// ---------------- hid = relu(feat @ d0_W + d0_b): 32 rows x 100 cols per block ----------------
__global__ __launch_bounds__(256) void k_hid(const float* __restrict__ feat,
    const float* __restrict__ d0W, const float* __restrict__ d0b, float* __restrict__ hid){
  __shared__ __align__(16) float fT[446*36];   // fT[ch*36 + r]
  int r0 = blockIdx.x * 32;
  int tid = threadIdx.x;
  for (int r = 0; r < 32; ++r){
    fT[tid*36 + r] = feat[(size_t)(r0 + r)*FCH + tid];
    if (tid < 190) fT[(tid + 256)*36 + r] = feat[(size_t)(r0 + r)*FCH + tid + 256];
  }
  __syncthreads();
  int cs = tid & 31, rq = tid >> 5;            // 32 c-slots (4 cols each), 8 row-quads
  if (cs < 25){
    float4 accv[4];
    #pragma unroll
    for (int jc = 0; jc < 4; ++jc) accv[jc] = make_float4(0.f,0.f,0.f,0.f);
    for (int k = 0; k < 446; ++k){
      float4 xv = *(const float4*)&fT[k*36 + 4*rq];
      float4 wv = *(const float4*)&d0W[k*100 + 4*cs];
      accv[0].x = fmaf(xv.x, wv.x, accv[0].x); accv[0].y = fmaf(xv.y, wv.x, accv[0].y);
      accv[0].z = fmaf(xv.z, wv.x, accv[0].z); accv[0].w = fmaf(xv.w, wv.x, accv[0].w);
      accv[1].x = fmaf(xv.x, wv.y, accv[1].x); accv[1].y = fmaf(xv.y, wv.y, accv[1].y);
      accv[1].z = fmaf(xv.z, wv.y, accv[1].z); accv[1].w = fmaf(xv.w, wv.y, accv[1].w);
      accv[2].x = fmaf(xv.x, wv.z, accv[2].x); accv[2].y = fmaf(xv.y, wv.z, accv[2].y);
      accv[2].z = fmaf(xv.z, wv.z, accv[2].z); accv[2].w = fmaf(xv.w, wv.z, accv[2].w);
      accv[3].x = fmaf(xv.x, wv.w, accv[3].x); accv[3].y = fmaf(xv.y, wv.w, accv[3].y);
      accv[3].z = fmaf(xv.z, wv.w, accv[3].z); accv[3].w = fmaf(xv.w, wv.w, accv[3].w);
    }
    #pragma unroll
    for (int i = 0; i < 4; ++i){
      int row = r0 + 4*rq + i;
      float4 o;
      float vi[4] = { i==0?accv[0].x:(i==1?accv[0].y:(i==2?accv[0].z:accv[0].w)),
                      i==0?accv[1].x:(i==1?accv[1].y:(i==2?accv[1].z:accv[1].w)),
                      i==0?accv[2].x:(i==1?accv[2].y:(i==2?accv[2].z:accv[2].w)),
                      i==0?accv[3].x:(i==1?accv[3].y:(i==2?accv[3].z:accv[3].w)) };
      o.x = fmaxf(vi[0] + d0b[4*cs+0], 0.0f);
      o.y = fmaxf(vi[1] + d0b[4*cs+1], 0.0f);
      o.z = fmaxf(vi[2] + d0b[4*cs+2], 0.0f);
      o.w = fmaxf(vi[3] + d0b[4*cs+3], 0.0f);
      *(float4*)&hid[(size_t)row*100 + 4*cs] = o;
    }
  }
}

// ---------------- pi + gumbel softmax -> d0,d1 (64 rows per block) ----------------
__global__ __launch_bounds__(128) void k_pi(const float* __restrict__ hid,
    const float* __restrict__ d1W, const float* __restrict__ d1b,
    const float* __restrict__ gum, float* __restrict__ d0a, float* __restrict__ d1a){
  __shared__ float hidL[64*100];
  int r0 = blockIdx.x * 64;
  int tid = threadIdx.x;
  for (int i = 0; i < 50; ++i) hidL[tid + 128*i] = hid[(size_t)r0*100 + tid + 128*i];
  __syncthreads();
  int r = tid >> 1, pp = tid & 1;
  float s = d1b[pp];
  for (int m = 0; m < 100; ++m) s = fmaf(hidL[r*100 + m], d1W[m*2 + pp], s);
  int row = r0 + r;
  float a = (s + gum[row*2 + pp]) / 1e-5f;
  float other = __shfl_xor(a, 1);
  float mx = fmaxf(a, other);
  float ea = expf(a - mx), eb = expf(other - mx);
  float d = ea / (ea + eb);
  if (pp == 0) d0a[row] = d; else d1a[row] = d;
}

// ---------------- xzT[t][col][b] = x[b][t] @ cell_Wx + cell_b ----------------
__global__ __launch_bounds__(256) void k_xz(const float* __restrict__ x,
    const float* __restrict__ Wx, const float* __restrict__ cb, float* __restrict__ xzT){
  __shared__ __align__(16) float xT[256*36];   // xT[e*36 + b]
  int t  = blockIdx.x >> 4;
  int c0 = (blockIdx.x & 15) * 128;
  int tid = threadIdx.x;
  for (int b = 0; b < 32; ++b){
    xT[tid*36 + b] = x[(b*Tz + t)*Ez + tid];
  }
  __syncthreads();
  int cs = tid & 31, rq = tid >> 5;
  float4 accv[4];
  #pragma unroll
  for (int jc = 0; jc < 4; ++jc) accv[jc] = make_float4(0.f,0.f,0.f,0.f);
  for (int e = 0; e < 256; ++e){
    float4 xv = *(const float4*)&xT[e*36 + 4*(rq & 7)];
    float4 wv = *(const float4*)&Wx[e*2048 + c0 + 4*cs];
    accv[0].x = fmaf(xv.x, wv.x, accv[0].x); accv[0].y = fmaf(xv.y, wv.x, accv[0].y);
    accv[0].z = fmaf(xv.z, wv.x, accv[0].z); accv[0].w = fmaf(xv.w, wv.x, accv[0].w);
    accv[1].x = fmaf(xv.x, wv.y, accv[1].x); accv[1].y = fmaf(xv.y, wv.y, accv[1].y);
    accv[1].z = fmaf(xv.z, wv.y, accv[1].z); accv[1].w = fmaf(xv.w, wv.y, accv[1].w);
    accv[2].x = fmaf(xv.x, wv.z, accv[2].x); accv[2].y = fmaf(xv.y, wv.z, accv[2].y);
    accv[2].z = fmaf(xv.z, wv.z, accv[2].z); accv[2].w = fmaf(xv.w, wv.z, accv[2].w);
    accv[3].x = fmaf(xv.x, wv.w, accv[3].x); accv[3].y = fmaf(xv.y, wv.w, accv[3].y);
    accv[3].z = fmaf(xv.z, wv.w, accv[3].z); accv[3].w = fmaf(xv.w, wv.w, accv[3].w);
  }
  #pragma unroll
  for (int jc = 0; jc < 4; ++jc){
    int col = c0 + 4*cs + jc;
    float bv = cb[col];
    float4 o = accv[jc];
    o.x += bv; o.y += bv; o.z += bv; o.w += bv;
    *(float4*)&xzT[((size_t)t*2048 + col)*32 + 4*rq] = o;
  }
}

// ---------------- persistent scan kernel ----------------
// 256 blocks x 1024 threads. group g = blockIdx&7, member m = blockIdx>>3 (0..31).
// Group handles batches 4g..4g+3; member owns hidden units [16m,16m+16) => 64 z-cols,
// weights resident in LDS. ALL cross-block traffic (h slices, barrier counter) uses
// RELAXED agent-scope atomics: plain sc-bit loads/stores served at the coherence
// point — NO buffer_inv / buffer_wbl2 anywhere (round-2's 30x regression).
// Ordering: __syncthreads() drains vmcnt in every wave before tid0 bumps the
// counter, so h stores are globally visible before the counter; consumers poll
// relaxed and then read h relaxed (producer order at the coherence point).
// LDS 145 KB => 1 block/CU => all 256 blocks co-resident => no deadlock.
__global__ __launch_bounds__(1024, 1) void k_scan(
    const float* __restrict__ WhT, const float* __restrict__ xzT,
    const float* __restrict__ d0a, const float* __restrict__ d1a,
    float* __restrict__ hG,              // [8 groups][2 bufs][4*512]
    unsigned int* __restrict__ barc,     // [8] counters, stride 64 uints
    float* __restrict__ out)
{
  __shared__ __align__(16) float wL[64*516];   // 132096 B
  __shared__ __align__(16) float hL[4*516];    // 8256 B
  __shared__ float part[1024];
  __shared__ float zL[256];

  int tid = threadIdx.x;
  int g = blockIdx.x & 7;
  int m = blockIdx.x >> 3;

  // one-time: load 64-col weight slice into LDS (128 KB)
  {
    int c = tid >> 4;                    // 0..63
    int f = tid & 15;
    int col = ((c >> 4) << 9) + (m << 4) + (c & 15);
    const float4* src = (const float4*)(WhT + (size_t)col*512);
    #pragma unroll
    for (int i = 0; i < 8; ++i){
      float4 v = src[f + 16*i];
      *(float4*)&wL[c*516 + 4*(f + 16*i)] = v;
    }
  }

  // thread mapping: tid = b + 4*c + 256*kq  (b:4, c:64 z-cols, kq:4 K-quarters)
  int b  = tid & 3;
  int c  = (tid >> 2) & 63;
  int kq = tid >> 8;
  int col = ((c >> 4) << 9) + (m << 4) + (c & 15);
  int Bg  = (g << 2) + b;                // global batch

  unsigned int* cnt = barc + g*64;
  float* hg0 = hG + (size_t)(g*2 + 0) * (4*512);
  float* hg1 = hG + (size_t)(g*2 + 1) * (4*512);

  float c_reg = 0.0f;                    // cell state, owned by tid<64

  for (int t = 0; t < Tz; ++t){
    const float* hcur = (t & 1) ? hg1 : hg0;
    float*       hnxt = (t & 1) ? hg0 : hg1;

    // stage group h (gen t) into LDS
    if (t == 0){
      if (tid < 512){
        int bb = tid >> 7, k4 = (tid & 127) << 2;
        *(float4*)&hL[bb*516 + k4] = make_float4(0.f,0.f,0.f,0.f);
      }
    } else {
      int i0 = tid, i1 = tid + 1024;
      float v0 = __hip_atomic_load(hcur + i0, __ATOMIC_RELAXED, __HIP_MEMORY_SCOPE_AGENT);
      float v1 = __hip_atomic_load(hcur + i1, __ATOMIC_RELAXED, __HIP_MEMORY_SCOPE_AGENT);
      hL[(i0 >> 9)*516 + (i0 & 511)] = v0;
      hL[(i1 >> 9)*516 + (i1 & 511)] = v1;
    }
    // prefetch xz + gate coefficients (latency hidden under barrier/matvec)
    float xzv = 0.0f;
    if (tid < 256) xzv = xzT[((size_t)t*2048 + col)*32 + Bg];
    float dv0 = 0.0f, dv1 = 0.0f;
    if (tid < 64){
      dv0 = d0a[t*32 + ((g << 2) + (tid & 3))];
      dv1 = d1a[t*32 + ((g << 2) + (tid & 3))];
    }
    __syncthreads();

    // partial matvec: z-col `col`, batch b, k in [kq*128, kq*128+128)
    float acc = 0.0f;
    const float* hp = &hL[b*516 + (kq << 7)];
    const float* wp = &wL[c*516 + (kq << 7)];
    #pragma unroll
    for (int kk = 0; kk < 16; ++kk){
      float4 hv0 = *(const float4*)(hp + 8*kk);
      float4 hv1 = *(const float4*)(hp + 8*kk + 4);
      float4 wv0 = *(const float4*)(wp + 8*kk);
      float4 wv1 = *(const float4*)(wp + 8*kk + 4);
      acc = fmaf(hv0.x, wv0.x, acc); acc = fmaf(hv0.y, wv0.y, acc);
      acc = fmaf(hv0.z, wv0.z, acc); acc = fmaf(hv0.w, wv0.w, acc);
      acc = fmaf(hv1.x, wv1.x, acc); acc = fmaf(hv1.y, wv1.y, acc);
      acc = fmaf(hv1.z, wv1.z, acc); acc = fmaf(hv1.w, wv1.w, acc);
    }
    part[tid] = acc;
    __syncthreads();

    if (tid < 256){
      zL[tid] = part[tid] + part[tid+256] + part[tid+512] + part[tid+768] + xzv;
    }
    __syncthreads();

    if (tid < 64){
      int jl = tid >> 2, bb = tid & 3;
      float zi = zL[bb + 4*jl];
      float zf = zL[bb + 4*jl + 64];
      float zg = zL[bb + 4*jl + 128];
      float zo = zL[bb + 4*jl + 192];
      float hold = hL[bb*516 + (m << 4) + jl];
      float ccand = sigf(zf)*c_reg + sigf(zi)*tanhfast(zg);
      float hcand = sigf(zo)*tanhfast(ccand);
      c_reg = dv0*ccand + dv1*c_reg;
      float hnew = dv0*hcand + dv1*hold;
      // publish h slice (relaxed agent atomic: sc-bit store, no cache maintenance)
      __hip_atomic_store(hnxt + bb*512 + (m << 4) + jl, hnew,
                         __ATOMIC_RELAXED, __HIP_MEMORY_SCOPE_AGENT);
      out[(size_t)((g << 2) + bb)*(Tz*Hz) + (size_t)t*Hz + (m << 4) + jl] = hcand;
    }

    if (t < Tz-1){
      __syncthreads();                   // every wave drains vmcnt here (compiler-guaranteed)
      if (tid == 0){
        __hip_atomic_fetch_add(cnt, 1u, __ATOMIC_RELAXED, __HIP_MEMORY_SCOPE_AGENT);
        unsigned int target = 32u*(unsigned)(t+1);
        while (__hip_atomic_load(cnt, __ATOMIC_RELAXED, __HIP_MEMORY_SCOPE_AGENT) < target)
          __builtin_amdgcn_s_sleep(1);
      }
      __syncthreads();
    }
  }
}

extern "C" void kernel_launch(void* const* d_in, const int* in_sizes, int n_in,
                              void* d_out, int out_size, void* d_ws, size_t ws_size,
                              hipStream_t stream)
{
  const float* x       = (const float*)d_in[0];
  const float* conv1_w = (const float*)d_in[1];
  const float* conv1_b = (const float*)d_in[2];
  const float* conv2_w = (const float*)d_in[3];
  const float* conv2_b = (const float*)d_in[4];
  const float* conv3_w = (const float*)d_in[5];
  const float* conv3_b = (const float*)d_in[6];
  const float* rev_Wx  = (const float*)d_in[7];
  const float* rev_Wh  = (const float*)d_in[8];
  const float* rev_b   = (const float*)d_in[9];
  const float* d0_W    = (const float*)d_in[10];
  const float* d0_b    = (const float*)d_in[11];
  const float* d1_W    = (const float*)d_in[12];
  const float* d1_b    = (const float*)d_in[13];
  const float* cell_Wx = (const float*)d_in[14];
  const float* cell_Wh = (const float*)d_in[15];
  const float* cell_b  = (const float*)d_in[16];
  const float* gumbel  = (const float*)d_in[17];
  float* out = (float*)d_out;

  char* ws = (char*)d_ws;
  size_t off = 0;
  float* xzT  = (float*)(ws + off); off += (size_t)Tz*2048*Bz*4;       // 134 MB
  float* feat = (float*)(ws + off); off += (size_t)Tz*Bz*FCH*4;        // 29 MB
  float* WhT  = (float*)(ws + off); off += (size_t)Hz*2048*4;          // 4 MB
  float* rxw  = (float*)(ws + off); off += (size_t)Tz*Bz*40*4;         // 2.6 MB
  float* hid  = (float*)(ws + off); off += (size_t)Tz*Bz*100*4;        // 6.5 MB
  float* d0a  = (float*)(ws + off); off += (size_t)Tz*Bz*4;
  float* d1a  = (float*)(ws + off); off += (size_t)Tz*Bz*4;
  float* hG   = (float*)(ws + off); off += (size_t)8*2*4*512*4;        // 128 KB
  unsigned int* barc = (unsigned int*)(ws + off); off += 8*64*4;       // 2 KB

  // zero-init: feat row T-1 (ff tail zeros; k_conv then writes its x-part), counters
  hipMemsetAsync(feat + (size_t)(Tz-1)*Bz*FCH, 0, Bz*FCH*4, stream);
  hipMemsetAsync(barc, 0, 8*64*4, stream);

  k_transpose_wh<<<4096, 256, 0, stream>>>(cell_Wh, WhT);
  k_conv<<<512, 256, 0, stream>>>(x, conv1_w, conv1_b, conv2_w, conv2_b,
                                  conv3_w, conv3_b, rev_Wx, feat, rxw);
  k_rev<<<32, 64, 0, stream>>>(rxw, rev_Wh, rev_b, feat);
  k_hid<<<512, 256, 0, stream>>>(feat, d0_W, d0_b, hid);
  k_pi<<<256, 128, 0, stream>>>(hid, d1_W, d1_b, gumbel, d0a, d1a);
  k_xz<<<8192, 256, 0, stream>>>(x, cell_Wx, cell_b, xzT);

  k_scan<<<256, 1024, 0, stream>>>(WhT, xzT, d0a, d1a, hG, barc, out);
}

// Round 4
// 3062.491 us; speedup vs baseline: 12.1763x; 1.0172x over previous
//
#include <hip/hip_runtime.h>
#include <math.h>

#define Bz 32
#define Tz 512
#define Ez 256
#define Hz 512
#define FCH 446   // 180 conv + 10 rev + 256 x

__device__ __forceinline__ float sigf(float x){ return 1.0f/(1.0f + __expf(-x)); }
__device__ __forceinline__ float tanhfast(float x){ return 1.0f - 2.0f/(__expf(2.0f*x) + 1.0f); }

// ---------------- WhT transpose: WhT[c*512 + k] = Wh[k*2048 + c] ----------------
__global__ __launch_bounds__(256) void k_transpose_wh(const float* __restrict__ Wh, float* __restrict__ WhT){
  int idx = blockIdx.x*256 + threadIdx.x;      // 512*2048 = 1,048,576
  int k = idx >> 11, c = idx & 2047;
  WhT[c*512 + k] = Wh[idx];
}

// ---------------- conv (3 kernels, SAME pad) + rxw = x_rev @ rev_Wx + x-copy into feat ----
__global__ __launch_bounds__(256) void k_conv(
    const float* __restrict__ x,
    const float* __restrict__ w1, const float* __restrict__ b1,
    const float* __restrict__ w2, const float* __restrict__ b2,
    const float* __restrict__ w3, const float* __restrict__ b3,
    const float* __restrict__ rwx,
    float* __restrict__ feat, float* __restrict__ rxw)
{
  __shared__ __align__(16) float xs[256*40];   // xs[e*40 + i] = x[b][t0-2+i], i in 0..35
  int b  = blockIdx.x >> 4;
  int t0 = (blockIdx.x & 15) * 32;
  int tid = threadIdx.x;
  for (int i = 0; i < 36; ++i){
    int t = t0 - 2 + i;
    xs[tid*40 + i] = (t >= 0 && t < Tz) ? x[(b*Tz + t)*Ez + tid] : 0.0f;
  }
  __syncthreads();
  // x-part of d0 input: feat[t][b][190+e] = x[b][t][e]
  for (int i = 0; i < 32; ++i){
    int t = t0 + i;
    feat[((size_t)t*Bz + b)*FCH + 190 + tid] = xs[tid*40 + i + 2];
  }
  int tq = tid & 7, cs = tid >> 3;             // 8 t-quads x 32 c-slots
  float acc[6][4];
  float racc[2][4];
  #pragma unroll
  for (int ci = 0; ci < 6; ++ci){
    int c = cs + 32*ci;
    float bv = 0.0f;
    if (c < 60) bv = b1[c];
    else if (c < 120) bv = b2[c-60];
    else if (c < 180) bv = b3[c-120];
    acc[ci][0]=acc[ci][1]=acc[ci][2]=acc[ci][3]=bv;
  }
  #pragma unroll
  for (int ji = 0; ji < 2; ++ji){ racc[ji][0]=racc[ji][1]=racc[ji][2]=racc[ji][3]=0.0f; }

  for (int e = 0; e < 256; ++e){
    const float* xr = &xs[e*40 + 4*tq];
    float4 wa = *(const float4*)(xr);
    float4 wb = *(const float4*)(xr + 4);
    float wd[8] = {wa.x, wa.y, wa.z, wa.w, wb.x, wb.y, wb.z, wb.w};
    #pragma unroll
    for (int ci = 0; ci < 6; ++ci){
      int c = cs + 32*ci;
      if (c < 60){
        #pragma unroll
        for (int k = 0; k < 3; ++k){
          float wv = w1[(k*256 + e)*60 + c];
          #pragma unroll
          for (int j = 0; j < 4; ++j) acc[ci][j] = fmaf(wd[1 + j + k], wv, acc[ci][j]);
        }
      } else if (c < 120){
        int cc = c - 60;
        #pragma unroll
        for (int k = 0; k < 4; ++k){
          float wv = w2[(k*256 + e)*60 + cc];
          #pragma unroll
          for (int j = 0; j < 4; ++j) acc[ci][j] = fmaf(wd[1 + j + k], wv, acc[ci][j]);
        }
      } else if (c < 180){
        int cc = c - 120;
        #pragma unroll
        for (int k = 0; k < 5; ++k){
          float wv = w3[(k*256 + e)*60 + cc];
          #pragma unroll
          for (int j = 0; j < 4; ++j) acc[ci][j] = fmaf(wd[j + k], wv, acc[ci][j]);
        }
      }
    }
    #pragma unroll
    for (int ji = 0; ji < 2; ++ji){
      int jc = cs + 32*ji;
      if (jc < 40){
        float wv = rwx[e*40 + jc];
        #pragma unroll
        for (int j = 0; j < 4; ++j) racc[ji][j] = fmaf(wd[2 + j], wv, racc[ji][j]);
      }
    }
  }
  #pragma unroll
  for (int ci = 0; ci < 6; ++ci){
    int c = cs + 32*ci;
    if (c < 180){
      #pragma unroll
      for (int j = 0; j < 4; ++j){
        int t = t0 + 4*tq + j;
        if (t >= 1) feat[((size_t)(t-1)*Bz + b)*FCH + c] = acc[ci][j];
      }
    }
  }
  #pragma unroll
  for (int ji = 0; ji < 2; ++ji){
    int jc = cs + 32*ji;
    if (jc < 40){
      #pragma unroll
      for (int j = 0; j < 4; ++j){
        int t = t0 + 4*tq + j;
        rxw[((size_t)(511 - t)*Bz + b)*40 + jc] = racc[ji][j];
      }
    }
  }
}

// ---------------- reverse LSTM (hidden 10), one wave per batch row ----------------
__global__ __launch_bounds__(64) void k_rev(const float* __restrict__ rxw,
    const float* __restrict__ revWh, const float* __restrict__ revb, float* __restrict__ feat){
  int b = blockIdx.x;
  int j = threadIdx.x;
  float wreg[10];
  float bias = 0.0f;
  #pragma unroll
  for (int k = 0; k < 10; ++k) wreg[k] = 0.0f;
  if (j < 40){
    bias = revb[j];
    #pragma unroll
    for (int k = 0; k < 10; ++k) wreg[k] = revWh[k*40 + j];
  }
  float h[10];
  #pragma unroll
  for (int k = 0; k < 10; ++k) h[k] = 0.0f;
  float c = 0.0f;
  for (int s = 0; s < Tz; ++s){
    float z = bias + ((j < 40) ? rxw[(s*Bz + b)*40 + j] : 0.0f);
    #pragma unroll
    for (int k = 0; k < 10; ++k) z = fmaf(h[k], wreg[k], z);
    float a = (j >= 20 && j < 30) ? tanhfast(z) : sigf(z);
    float af = __shfl(a, j + 10);
    float ag = __shfl(a, j + 20);
    float ao = __shfl(a, j + 30);
    if (j < 10) c = af*c + a*ag;
    float hn = ao * tanhfast(c);
    #pragma unroll
    for (int k = 0; k < 10; ++k) h[k] = __shfl(hn, k);
    if (j < 10 && s >= 1) feat[((size_t)(s-1)*Bz + b)*FCH + 180 + j] = hn;
  }
}

// ---------------- hid = relu(feat @ d0_W + d0_b): 32 rows x 100 cols per block ----------------
__global__ __launch_bounds__(256) void k_hid(const float* __restrict__ feat,
    const float* __restrict__ d0W, const float* __restrict__ d0b, float* __restrict__ hid){
  __shared__ __align__(16) float fT[446*36];   // fT[ch*36 + r]
  int r0 = blockIdx.x * 32;
  int tid = threadIdx.x;
  for (int r = 0; r < 32; ++r){
    fT[tid*36 + r] = feat[(size_t)(r0 + r)*FCH + tid];
    if (tid < 190) fT[(tid + 256)*36 + r] = feat[(size_t)(r0 + r)*FCH + tid + 256];
  }
  __syncthreads();
  int cs = tid & 31, rq = tid >> 5;            // 32 c-slots (4 cols each), 8 row-quads
  if (cs < 25){
    float4 accv[4];
    #pragma unroll
    for (int jc = 0; jc < 4; ++jc) accv[jc] = make_float4(0.f,0.f,0.f,0.f);
    for (int k = 0; k < 446; ++k){
      float4 xv = *(const float4*)&fT[k*36 + 4*rq];
      float4 wv = *(const float4*)&d0W[k*100 + 4*cs];
      accv[0].x = fmaf(xv.x, wv.x, accv[0].x); accv[0].y = fmaf(xv.y, wv.x, accv[0].y);
      accv[0].z = fmaf(xv.z, wv.x, accv[0].z); accv[0].w = fmaf(xv.w, wv.x, accv[0].w);
      accv[1].x = fmaf(xv.x, wv.y, accv[1].x); accv[1].y = fmaf(xv.y, wv.y, accv[1].y);
      accv[1].z = fmaf(xv.z, wv.y, accv[1].z); accv[1].w = fmaf(xv.w, wv.y, accv[1].w);
      accv[2].x = fmaf(xv.x, wv.z, accv[2].x); accv[2].y = fmaf(xv.y, wv.z, accv[2].y);
      accv[2].z = fmaf(xv.z, wv.z, accv[2].z); accv[2].w = fmaf(xv.w, wv.z, accv[2].w);
      accv[3].x = fmaf(xv.x, wv.w, accv[3].x); accv[3].y = fmaf(xv.y, wv.w, accv[3].y);
      accv[3].z = fmaf(xv.z, wv.w, accv[3].z); accv[3].w = fmaf(xv.w, wv.w, accv[3].w);
    }
    #pragma unroll
    for (int i = 0; i < 4; ++i){
      int row = r0 + 4*rq + i;
      float4 o;
      float vi[4] = { i==0?accv[0].x:(i==1?accv[0].y:(i==2?accv[0].z:accv[0].w)),
                      i==0?accv[1].x:(i==1?accv[1].y:(i==2?accv[1].z:accv[1].w)),
                      i==0?accv[2].x:(i==1?accv[2].y:(i==2?accv[2].z:accv[2].w)),
                      i==0?accv[3].x:(i==1?accv[3].y:(i==2?accv[3].z:accv[3].w)) };
      o.x = fmaxf(vi[0] + d0b[4*cs+0], 0.0f);
      o.y = fmaxf(vi[1] + d0b[4*cs+1], 0.0f);
      o.z = fmaxf(vi[2] + d0b[4*cs+2], 0.0f);
      o.w = fmaxf(vi[3] + d0b[4*cs+3], 0.0f);
      *(float4*)&hid[(size_t)row*100 + 4*cs] = o;
    }
  }
}

// ---------------- pi + gumbel softmax -> d0,d1 (64 rows per block) ----------------
__global__ __launch_bounds__(128) void k_pi(const float* __restrict__ hid,
    const float* __restrict__ d1W, const float* __restrict__ d1b,
    const float* __restrict__ gum, float* __restrict__ d0a, float* __restrict__ d1a){
  __shared__ float hidL[64*100];
  int r0 = blockIdx.x * 64;
  int tid = threadIdx.x;
  for (int i = 0; i < 50; ++i) hidL[tid + 128*i] = hid[(size_t)r0*100 + tid + 128*i];
  __syncthreads();
  int r = tid >> 1, pp = tid & 1;
  float s = d1b[pp];
  for (int m = 0; m < 100; ++m) s = fmaf(hidL[r*100 + m], d1W[m*2 + pp], s);
  int row = r0 + r;
  float a = (s + gum[row*2 + pp]) / 1e-5f;
  float other = __shfl_xor(a, 1);
  float mx = fmaxf(a, other);
  float ea = expf(a - mx), eb = expf(other - mx);
  float d = ea / (ea + eb);
  if (pp == 0) d0a[row] = d; else d1a[row] = d;
}

// ---------------- xzG[((g*T + t)*2048 + col)*4 + b'] = x[b][t] @ cell_Wx + cell_b ----------
// b = 4g + b'. Per-group-blocked layout: each 128B line belongs to exactly one scan block,
// and group g's region is read only by XCD g (blockIdx%8 round-robin) => no cross-XCD refetch.
// Block order t-inner so 512 consecutive blocks share one 128KB Wx slice in L2.
__global__ __launch_bounds__(256) void k_xz(const float* __restrict__ x,
    const float* __restrict__ Wx, const float* __restrict__ cb, float* __restrict__ xzG){
  __shared__ __align__(16) float xT[256*36];   // xT[e*36 + b]
  int t  = blockIdx.x & 511;
  int c0 = (blockIdx.x >> 9) * 128;
  int tid = threadIdx.x;
  for (int b = 0; b < 32; ++b){
    xT[tid*36 + b] = x[(b*Tz + t)*Ez + tid];
  }
  __syncthreads();
  int cs = tid & 31, rq = tid >> 5;            // 32 col-slots (4 cols), 8 batch-quads (=groups)
  float4 accv[4];
  #pragma unroll
  for (int jc = 0; jc < 4; ++jc) accv[jc] = make_float4(0.f,0.f,0.f,0.f);
  for (int e = 0; e < 256; ++e){
    float4 xv = *(const float4*)&xT[e*36 + 4*rq];
    float4 wv = *(const float4*)&Wx[e*2048 + c0 + 4*cs];
    accv[0].x = fmaf(xv.x, wv.x, accv[0].x); accv[0].y = fmaf(xv.y, wv.x, accv[0].y);
    accv[0].z = fmaf(xv.z, wv.x, accv[0].z); accv[0].w = fmaf(xv.w, wv.x, accv[0].w);
    accv[1].x = fmaf(xv.x, wv.y, accv[1].x); accv[1].y = fmaf(xv.y, wv.y, accv[1].y);
    accv[1].z = fmaf(xv.z, wv.y, accv[1].z); accv[1].w = fmaf(xv.w, wv.y, accv[1].w);
    accv[2].x = fmaf(xv.x, wv.z, accv[2].x); accv[2].y = fmaf(xv.y, wv.z, accv[2].y);
    accv[2].z = fmaf(xv.z, wv.z, accv[2].z); accv[2].w = fmaf(xv.w, wv.z, accv[2].w);
    accv[3].x = fmaf(xv.x, wv.w, accv[3].x); accv[3].y = fmaf(xv.y, wv.w, accv[3].y);
    accv[3].z = fmaf(xv.z, wv.w, accv[3].z); accv[3].w = fmaf(xv.w, wv.w, accv[3].w);
  }
  #pragma unroll
  for (int jc = 0; jc < 4; ++jc){
    int col = c0 + 4*cs + jc;
    float bv = cb[col];
    float4 o = accv[jc];
    o.x += bv; o.y += bv; o.z += bv; o.w += bv;
    // group rq, batches 4rq..4rq+3 (accv lanes are batch 4rq+{0..3})
    *(float4*)&xzG[(((size_t)rq*Tz + t)*2048 + col)*4] = o;
  }
}

// ---------------- persistent scan kernel ----------------
// 256 blocks x 1024 threads. group g = blockIdx&7 (XCD under round-robin), member
// m = blockIdx>>3 (0..31). Group = batches 4g..4g+3; member owns hidden units
// [16m,16m+16) => 64 z-cols. Wh slice lives in VGPRs (32/thread): LDS traffic per
// step is h-broadcast reads + 66KB partial buffer (was 1MB in round 3 => LDS-BW bound).
// Cross-block h exchange: RELAXED agent-scope atomics only (round-2 lesson: acquire/
// fence => buffer_inv storms). __syncthreads' vmcnt drain orders publish before the
// group counter bump. LDS 76KB, VGPR<=128 => 16 waves/CU, 1 block/CU co-resident.
__global__ __launch_bounds__(1024, 1) void k_scan(
    const float* __restrict__ WhT, const float* __restrict__ xzG,
    const float* __restrict__ d0a, const float* __restrict__ d1a,
    float* __restrict__ hG,              // [8 groups][2 bufs][4*512]
    unsigned int* __restrict__ barc,     // [8] counters, stride 64 uints
    float* __restrict__ out)
{
  __shared__ __align__(16) float part[64*260]; // kseg-major, stride 260 (=4 mod 32)
  __shared__ __align__(16) float hL[4*520];    // h staging, row stride 520
  __shared__ float zL[256];
  __shared__ float hcandL[64];

  int tid = threadIdx.x;
  int g = blockIdx.x & 7;
  int m = blockIdx.x >> 3;

  // thread tiling: cq = tid&15 (4 cols each), kseg = tid>>4 (8 k each)
  int cq = tid & 15;
  int kseg = tid >> 4;

  // one-time: Wh slice into registers (4 cols x 8 k per thread = 32 VGPR)
  float wreg[4][8];
  #pragma unroll
  for (int ciq = 0; ciq < 4; ++ciq){
    int c = 4*cq + ciq;
    int col = ((c >> 4) << 9) + (m << 4) + (c & 15);
    const float4* wp = (const float4*)(WhT + (size_t)col*512 + kseg*8);
    float4 a = wp[0], bq = wp[1];
    wreg[ciq][0]=a.x;  wreg[ciq][1]=a.y;  wreg[ciq][2]=a.z;  wreg[ciq][3]=a.w;
    wreg[ciq][4]=bq.x; wreg[ciq][5]=bq.y; wreg[ciq][6]=bq.z; wreg[ciq][7]=bq.w;
  }

  // reducer role (tid<256): r = tid = c*4 + b
  int rc = tid >> 2, rb = tid & 3;
  int rcol = ((rc >> 4) << 9) + (m << 4) + (rc & 15);
  size_t xzbase = ((size_t)g*Tz)*8192 + (size_t)rcol*4 + rb;

  unsigned int* cnt = barc + g*64;
  float* hg0 = hG + (size_t)(g*2 + 0) * (4*512);
  float* hg1 = hG + (size_t)(g*2 + 1) * (4*512);

  float c_reg = 0.0f;                    // cell state, owned by tid<64 (bb=tid&3, jl=tid>>2)

  for (int t = 0; t < Tz; ++t){
    const float* hcur = (t & 1) ? hg1 : hg0;
    float*       hnxt = (t & 1) ? hg0 : hg1;

    // stage group h (gen t) into LDS; prefetch xz + gate coeffs
    if (t == 0){
      int i0 = tid, i1 = tid + 1024;
      hL[(i0 >> 9)*520 + (i0 & 511)] = 0.0f;
      hL[(i1 >> 9)*520 + (i1 & 511)] = 0.0f;
    } else {
      int i0 = tid, i1 = tid + 1024;
      float v0 = __hip_atomic_load(hcur + i0, __ATOMIC_RELAXED, __HIP_MEMORY_SCOPE_AGENT);
      float v1 = __hip_atomic_load(hcur + i1, __ATOMIC_RELAXED, __HIP_MEMORY_SCOPE_AGENT);
      hL[(i0 >> 9)*520 + (i0 & 511)] = v0;
      hL[(i1 >> 9)*520 + (i1 & 511)] = v1;
    }
    float xzv = 0.0f;
    if (tid < 256) xzv = xzG[xzbase + (size_t)t*8192];
    float dv0 = 0.0f, dv1 = 0.0f;
    if (tid < 64){
      dv0 = d0a[t*32 + ((g << 2) + (tid & 3))];
      dv1 = d1a[t*32 + ((g << 2) + (tid & 3))];
    }
    __syncthreads();

    // matvec: acc[ciq][b] over k in [kseg*8, kseg*8+8); h reads are 16-lane broadcasts
    float acc[4][4];
    #pragma unroll
    for (int ciq = 0; ciq < 4; ++ciq)
      #pragma unroll
      for (int b = 0; b < 4; ++b) acc[ciq][b] = 0.0f;
    #pragma unroll
    for (int b = 0; b < 4; ++b){
      const float4* hp = (const float4*)&hL[b*520 + kseg*8];
      float4 h0 = hp[0], h1 = hp[1];
      float hv[8] = {h0.x,h0.y,h0.z,h0.w,h1.x,h1.y,h1.z,h1.w};
      #pragma unroll
      for (int j = 0; j < 8; ++j){
        #pragma unroll
        for (int ciq = 0; ciq < 4; ++ciq)
          acc[ciq][b] = fmaf(wreg[ciq][j], hv[j], acc[ciq][b]);
      }
    }
    {
      float* pw = &part[kseg*260 + 16*cq];
      *(float4*)(pw +  0) = make_float4(acc[0][0],acc[0][1],acc[0][2],acc[0][3]);
      *(float4*)(pw +  4) = make_float4(acc[1][0],acc[1][1],acc[1][2],acc[1][3]);
      *(float4*)(pw +  8) = make_float4(acc[2][0],acc[2][1],acc[2][2],acc[2][3]);
      *(float4*)(pw + 12) = make_float4(acc[3][0],acc[3][1],acc[3][2],acc[3][3]);
    }
    __syncthreads();

    // reduce 64 partials per z-element (4 independent chains for ILP)
    if (tid < 256){
      float s0 = 0.f, s1 = 0.f, s2 = 0.f, s3 = 0.f;
      #pragma unroll
      for (int s = 0; s < 64; s += 4){
        s0 += part[(s+0)*260 + tid];
        s1 += part[(s+1)*260 + tid];
        s2 += part[(s+2)*260 + tid];
        s3 += part[(s+3)*260 + tid];
      }
      zL[tid] = (s0+s1)+(s2+s3) + xzv;
    }
    __syncthreads();

    // gates + publish (wave 0)
    if (tid < 64){
      int jl = tid >> 2, bb = tid & 3;
      float zi = zL[bb + 4*jl];
      float zf = zL[bb + 4*jl + 64];
      float zg = zL[bb + 4*jl + 128];
      float zo = zL[bb + 4*jl + 192];
      float hold = hL[bb*520 + (m << 4) + jl];
      float ccand = sigf(zf)*c_reg + sigf(zi)*tanhfast(zg);
      float hcand = sigf(zo)*tanhfast(ccand);
      c_reg = dv0*ccand + dv1*c_reg;
      float hnew = dv0*hcand + dv1*hold;
      hcandL[bb*16 + jl] = hcand;
      __hip_atomic_store(hnxt + bb*512 + (m << 4) + jl, hnew,
                         __ATOMIC_RELAXED, __HIP_MEMORY_SCOPE_AGENT);
    }
    __syncthreads();                     // drains wave 0's publishes (vmcnt) + hcandL visible

    // out store by wave 1 (overlaps tid0's barrier wait)
    if (tid >= 64 && tid < 80){
      int idx = tid - 64; int bb = idx >> 2, q = idx & 3;
      float4 v = *(const float4*)&hcandL[bb*16 + 4*q];
      *(float4*)(out + (size_t)((g << 2) + bb)*(Tz*Hz) + (size_t)t*Hz + (m << 4) + 4*q) = v;
    }
    if (t < Tz-1){
      if (tid == 0){
        __hip_atomic_fetch_add(cnt, 1u, __ATOMIC_RELAXED, __HIP_MEMORY_SCOPE_AGENT);
        unsigned int target = 32u*(unsigned)(t+1);
        while (__hip_atomic_load(cnt, __ATOMIC_RELAXED, __HIP_MEMORY_SCOPE_AGENT) < target)
          __builtin_amdgcn_s_sleep(1);
      }
      __syncthreads();
    }
  }
}

extern "C" void kernel_launch(void* const* d_in, const int* in_sizes, int n_in,
                              void* d_out, int out_size, void* d_ws, size_t ws_size,
                              hipStream_t stream)
{
  const float* x       = (const float*)d_in[0];
  const float* conv1_w = (const float*)d_in[1];
  const float* conv1_b = (const float*)d_in[2];
  const float* conv2_w = (const float*)d_in[3];
  const float* conv2_b = (const float*)d_in[4];
  const float* conv3_w = (const float*)d_in[5];
  const float* conv3_b = (const float*)d_in[6];
  const float* rev_Wx  = (const float*)d_in[7];
  const float* rev_Wh  = (const float*)d_in[8];
  const float* rev_b   = (const float*)d_in[9];
  const float* d0_W    = (const float*)d_in[10];
  const float* d0_b    = (const float*)d_in[11];
  const float* d1_W    = (const float*)d_in[12];
  const float* d1_b    = (const float*)d_in[13];
  const float* cell_Wx = (const float*)d_in[14];
  const float* cell_Wh = (const float*)d_in[15];
  const float* cell_b  = (const float*)d_in[16];
  const float* gumbel  = (const float*)d_in[17];
  float* out = (float*)d_out;

  char* ws = (char*)d_ws;
  size_t off = 0;
  float* xzG  = (float*)(ws + off); off += (size_t)Tz*2048*Bz*4;       // 134 MB
  float* feat = (float*)(ws + off); off += (size_t)Tz*Bz*FCH*4;        // 29 MB
  float* WhT  = (float*)(ws + off); off += (size_t)Hz*2048*4;          // 4 MB
  float* rxw  = (float*)(ws + off); off += (size_t)Tz*Bz*40*4;         // 2.6 MB
  float* hid  = (float*)(ws + off); off += (size_t)Tz*Bz*100*4;        // 6.5 MB
  float* d0a  = (float*)(ws + off); off += (size_t)Tz*Bz*4;
  float* d1a  = (float*)(ws + off); off += (size_t)Tz*Bz*4;
  float* hG   = (float*)(ws + off); off += (size_t)8*2*4*512*4;        // 128 KB
  unsigned int* barc = (unsigned int*)(ws + off); off += 8*64*4;       // 2 KB

  // zero-init: feat row T-1 (ff tail zeros; k_conv writes its x-part), counters
  hipMemsetAsync(feat + (size_t)(Tz-1)*Bz*FCH, 0, Bz*FCH*4, stream);
  hipMemsetAsync(barc, 0, 8*64*4, stream);

  k_transpose_wh<<<4096, 256, 0, stream>>>(cell_Wh, WhT);
  k_conv<<<512, 256, 0, stream>>>(x, conv1_w, conv1_b, conv2_w, conv2_b,
                                  conv3_w, conv3_b, rev_Wx, feat, rxw);
  k_rev<<<32, 64, 0, stream>>>(rxw, rev_Wh, rev_b, feat);
  k_hid<<<512, 256, 0, stream>>>(feat, d0_W, d0_b, hid);
  k_pi<<<256, 128, 0, stream>>>(hid, d1_W, d1_b, gumbel, d0a, d1a);
  k_xz<<<8192, 256, 0, stream>>>(x, cell_Wx, cell_b, xzG);

  k_scan<<<256, 1024, 0, stream>>>(WhT, xzG, d0a, d1a, hG, barc, out);
}